// Round 16
// baseline (342.656 us; speedup 1.0000x reference)
//
#include <hip/hip_runtime.h>
#include <hip/hip_bf16.h>

// Problem constants (from setup_inputs)
#define N_NODES   100000
#define E_EDGES   1000000
#define H_DIM     128
#define NCHUNK    31250        // E / 32 edges per superchunk
#define GRID      256          // 256 blocks x 8 waves = 2048 wave-streams (r13-proven)
#define NWAVES    2048

typedef short bf16x8 __attribute__((ext_vector_type(8)));
typedef float f32x4  __attribute__((ext_vector_type(4)));

__device__ inline unsigned short f2bf(float f) {      // scalar RNE (cold paths only)
    unsigned u = __builtin_bit_cast(unsigned, f);
    u += 0x7fffu + ((u >> 16) & 1u);
    return (unsigned short)(u >> 16);
}

// Packed RNE f32x2 -> bf16x2 (r9-proven: cut VALUBusy 51->34)
__device__ inline unsigned pk2(float lo, float hi) {
    __hip_bfloat162 t = __float22bfloat162_rn(make_float2(lo, hi));
    unsigned lo16 = __bfloat16_as_ushort(t.x);
    unsigned hi16 = __bfloat16_as_ushort(t.y);
    return lo16 | (hi16 << 16);
}

__device__ inline f32x4 mfma16(bf16x8 a, bf16x8 b, f32x4 c) {
    return __builtin_amdgcn_mfma_f32_16x16x32_bf16(a, b, c, 0, 0, 0);
}

// Weights -> [j][k] bf16; x -> bf16 table (r11-proven: FETCH 58->17 MB); zero stats.
__global__ void prep_k(const float* __restrict__ x,
                       const float* __restrict__ W1, const float* __restrict__ W2,
                       unsigned short* __restrict__ wt1raw, unsigned short* __restrict__ wt2raw,
                       unsigned short* __restrict__ xb, float* __restrict__ stats) {
    int i = blockIdx.x * 256 + threadIdx.x;
    if (i < 512)   stats[i] = 0.f;                    // stats1[256] ++ stats2[256]
    if (i < 4096)  wt1raw[i] = f2bf(W1[(i & 31)  * H_DIM + (i >> 5)]);
    if (i < 16384) wt2raw[i] = f2bf(W2[(i & 127) * H_DIM + (i >> 7)]);
    const float4* x4 = (const float4*)x;
    uint2* xb2 = (uint2*)xb;
    for (int t = i; t < (N_NODES * 16) / 4; t += gridDim.x * 256) {
        float4 v = x4[t];
        uint2 o; o.x = pk2(v.x, v.y); o.y = pk2(v.z, v.w);
        xb2[t] = o;
    }
}

// stats -> BN fold. Parallel: block j (128 blocks), thread kp (128 threads).
__global__ void fold_k(const float* __restrict__ stats, const float* __restrict__ W, int K,
                       const float* __restrict__ gamma, const float* __restrict__ beta,
                       float* __restrict__ cvec, unsigned short* __restrict__ wtf) {
    int j  = blockIdx.x;
    int kp = threadIdx.x;
    const float invE = 1.0f / (float)E_EDGES;
    float s = stats[j], q = stats[128 + j];
    float mu  = s * invE;
    float var = fmaxf(q * invE - mu * mu, 0.f);        // clamp: corruption -> finite, not NaN
    float a   = gamma[j] * rsqrtf(var + 1e-5f);
    if (kp == 0) cvec[j] = beta[j] - mu * a;           // layer bias cancels inside BN
    if (kp < K)  wtf[j * K + kp] = f2bf(W[kp * H_DIM + j] * a);
}

// MODE 0: stats of d1 = ef@W1                         (raw wt1)
// MODE 1: h1' = relu(ef@W1f+c1); stats of d2 = h1'@W2 (raw wt2)
// MODE 2: full folded pipeline -> out = relu(h2')@W3 + b3
// 512-thread blocks (8 waves), r13-proven shape.
template<int MODE>
__global__ __launch_bounds__(512, 2) void mlp_pass(
    const unsigned short* __restrict__ xb, const int* __restrict__ ei,
    const unsigned short* __restrict__ wt1, const float* __restrict__ c1,
    const unsigned short* __restrict__ wt2, const float* __restrict__ c2,
    const float* __restrict__ w3, const float* __restrict__ b3,
    float* __restrict__ stats, float* __restrict__ out) {

    const int tid = threadIdx.x;
    const int w  = tid >> 6;        // wave 0..7
    const int l  = tid & 63;
    const int lm = l & 15;          // edge slot / row-within-tile
    const int lg = l >> 4;          // k-group (0..3)

    __shared__ __align__(16) unsigned char s_w2_[(MODE >= 1) ? 32768 : 16];
    __shared__ __align__(16) unsigned char s_h1_[(MODE >= 1) ? 65536 : 16];
    __shared__ float red_[(MODE <= 1) ? 2048 : 4];

    // Hoist layer-1 A fragments: A[j][k], j = jt*16+lm, k = lg*8..+7
    bf16x8 a1f[8];
#pragma unroll
    for (int jt = 0; jt < 8; jt++)
        a1f[jt] = *(const bf16x8*)(wt1 + (jt * 16 + lm) * 32 + lg * 8);

    if constexpr (MODE >= 1) {
        // Stage Wt2 [128][128] bf16 into LDS; 16B unit u of row j at slot u^(j&15)
        const uint4* g = (const uint4*)wt2;
        for (int i = tid; i < 2048; i += 512) {
            int j = i >> 4, u = i & 15;
            *(uint4*)(s_w2_ + j * 256 + ((u ^ (j & 15)) << 4)) = g[i];
        }
        __syncthreads();
    }

    float accS[8][4], accQ[8][4];
    if constexpr (MODE <= 1) {
#pragma unroll
        for (int jt = 0; jt < 8; jt++)
#pragma unroll
            for (int r = 0; r < 4; r++) { accS[jt][r] = 0.f; accQ[jt][r] = 0.f; }
    }

    unsigned char* myh = s_h1_ + w * 8192;
    const int eoff = (l >> 5) * E_EDGES;   // 0 -> src(row), 1 -> dst(col)
    const int f0   = (lg & 1) * 8;         // feature sub-offset within x row

    float b3v = 0.f;
    if constexpr (MODE == 2) b3v = b3[0];

    for (int sc = blockIdx.x * 8 + w; sc < NCHUNK; sc += NWAVES) {
        const int base = sc * 32;
        int iA = ei[eoff + base + lm];
        int iB = ei[eoff + base + 16 + lm];
        iA = min(max(iA, 0), N_NODES - 1);
        iB = min(max(iB, 0), N_NODES - 1);
        bf16x8 befA = *(const bf16x8*)(xb + (size_t)iA * 16 + f0);
        bf16x8 befB = *(const bf16x8*)(xb + (size_t)iB * 16 + f0);

        if constexpr (MODE == 0) {
#pragma unroll
            for (int jt = 0; jt < 8; jt++) {
                f32x4 z = {0.f, 0.f, 0.f, 0.f};
                f32x4 dA = mfma16(a1f[jt], befA, z);
                f32x4 dB = mfma16(a1f[jt], befB, z);
#pragma unroll
                for (int r = 0; r < 4; r++) {
                    accS[jt][r] += dA[r] + dB[r];
                    accQ[jt][r] += dA[r] * dA[r] + dB[r] * dB[r];
                }
            }
        } else {
            // ---- layer 1 (folded) + relu -> LDS (swizzled, pk2 packing) ----
#pragma unroll
            for (int jt = 0; jt < 8; jt++) {
                f32x4 z = {0.f, 0.f, 0.f, 0.f};
                f32x4 dA = mfma16(a1f[jt], befA, z);
                f32x4 dB = mfma16(a1f[jt], befB, z);
                float4 cv = *(const float4*)(c1 + jt * 16 + lg * 4);
                int uu  = jt * 2 + (lg >> 1);
                int off = lm * 256 + ((uu ^ (lm & 7)) << 4) + (lg & 1) * 8;
                {
                    uint2 pkv;
                    pkv.x = pk2(fmaxf(dA[0] + cv.x, 0.f), fmaxf(dA[1] + cv.y, 0.f));
                    pkv.y = pk2(fmaxf(dA[2] + cv.z, 0.f), fmaxf(dA[3] + cv.w, 0.f));
                    *(uint2*)(myh + off) = pkv;
                }
                {
                    uint2 pkv;
                    pkv.x = pk2(fmaxf(dB[0] + cv.x, 0.f), fmaxf(dB[1] + cv.y, 0.f));
                    pkv.y = pk2(fmaxf(dB[2] + cv.z, 0.f), fmaxf(dB[3] + cv.w, 0.f));
                    *(uint2*)(myh + 4096 + off) = pkv;
                }
            }
            // NOTE: no manual lgkmcnt(0) drain — the ds_reads below are ordinary
            // compiler-visible loads; the compiler inserts the (finer) waits and
            // can overlap the independent s_w2_ reads with h1-write latency.

            // ---- read back h1' B fragments ----
            bf16x8 hbA[4], hbB[4];
#pragma unroll
            for (int kt = 0; kt < 4; kt++) {
                int offr = lm * 256 + (((kt * 4 + lg) ^ (lm & 7)) << 4);
                hbA[kt] = *(const bf16x8*)(myh + offr);
                hbB[kt] = *(const bf16x8*)(myh + 4096 + offr);
            }

            // ---- layer 2 (K=128 as 4 x K=32, from LDS-staged W2) ----
            float sA = 0.f, sB = 0.f;
#pragma unroll
            for (int j2t = 0; j2t < 8; j2t++) {
                f32x4 dA2 = {0.f, 0.f, 0.f, 0.f}, dB2 = {0.f, 0.f, 0.f, 0.f};
                const int rb = (j2t * 16 + lm) * 256;
#pragma unroll
                for (int kt = 0; kt < 4; kt++) {
                    bf16x8 a2 = *(const bf16x8*)(s_w2_ + rb + (((kt * 4 + lg) ^ lm) << 4));
                    dA2 = mfma16(a2, hbA[kt], dA2);
                    dB2 = mfma16(a2, hbB[kt], dB2);
                }
                if constexpr (MODE == 1) {
#pragma unroll
                    for (int r = 0; r < 4; r++) {
                        accS[j2t][r] += dA2[r] + dB2[r];
                        accQ[j2t][r] += dA2[r] * dA2[r] + dB2[r] * dB2[r];
                    }
                } else {
                    float4 cv = *(const float4*)(c2 + j2t * 16 + lg * 4);
                    float4 wv = *(const float4*)(w3 + j2t * 16 + lg * 4);
                    sA = fmaf(fmaxf(dA2[0] + cv.x, 0.f), wv.x, sA);
                    sA = fmaf(fmaxf(dA2[1] + cv.y, 0.f), wv.y, sA);
                    sA = fmaf(fmaxf(dA2[2] + cv.z, 0.f), wv.z, sA);
                    sA = fmaf(fmaxf(dA2[3] + cv.w, 0.f), wv.w, sA);
                    sB = fmaf(fmaxf(dB2[0] + cv.x, 0.f), wv.x, sB);
                    sB = fmaf(fmaxf(dB2[1] + cv.y, 0.f), wv.y, sB);
                    sB = fmaf(fmaxf(dB2[2] + cv.z, 0.f), wv.z, sB);
                    sB = fmaf(fmaxf(dB2[3] + cv.w, 0.f), wv.w, sB);
                }
            }
            if constexpr (MODE == 2) {
                sA += __shfl_xor(sA, 16); sA += __shfl_xor(sA, 32);
                sB += __shfl_xor(sB, 16); sB += __shfl_xor(sB, 32);
                if (lg == 0) {
                    out[base + lm]      = sA + b3v;
                    out[base + 16 + lm] = sB + b3v;
                }
            }
        }
    }

    if constexpr (MODE <= 1) {
        __syncthreads();
#pragma unroll
        for (int jt = 0; jt < 8; jt++)
#pragma unroll
            for (int r = 0; r < 4; r++) {
                float v = accS[jt][r];
                v += __shfl_xor(v, 1); v += __shfl_xor(v, 2);
                v += __shfl_xor(v, 4); v += __shfl_xor(v, 8);
                float q = accQ[jt][r];
                q += __shfl_xor(q, 1); q += __shfl_xor(q, 2);
                q += __shfl_xor(q, 4); q += __shfl_xor(q, 8);
                if (lm == 0) {
                    int j = jt * 16 + lg * 4 + r;
                    red_[w * 256 + j]       = v;
                    red_[w * 256 + 128 + j] = q;
                }
            }
        __syncthreads();
        if (tid < 256) {
            float acc = 0.f;
#pragma unroll
            for (int t = 0; t < 8; t++) acc += red_[t * 256 + tid];
            atomicAdd(&stats[tid], acc);
        }
    }
}

extern "C" void kernel_launch(void* const* d_in, const int* in_sizes, int n_in,
                              void* d_out, int out_size, void* d_ws, size_t ws_size,
                              hipStream_t stream) {
    const float* x   = (const float*)d_in[0];
    const int*   ei  = (const int*)d_in[1];     // harness passes integer inputs as int32
    const float* W1  = (const float*)d_in[2];
    const float* g1  = (const float*)d_in[4];
    const float* be1 = (const float*)d_in[5];
    const float* W2  = (const float*)d_in[6];
    const float* g2  = (const float*)d_in[8];
    const float* be2 = (const float*)d_in[9];
    const float* W3  = (const float*)d_in[10];
    const float* b3  = (const float*)d_in[11];
    float* out = (float*)d_out;

    char* ws = (char*)d_ws;                                     // 84992 + 3.2 MB
    float* stats1           = (float*)ws;                       // [256]
    float* stats2           = (float*)(ws + 1024);              // [256]
    float* c1               = (float*)(ws + 2048);              // [128]
    float* c2               = (float*)(ws + 2560);              // [128]
    unsigned short* wt1raw  = (unsigned short*)(ws + 3072);     // [128][32]  bf16
    unsigned short* wt1f    = (unsigned short*)(ws + 11264);    // [128][32]  bf16
    unsigned short* wt2raw  = (unsigned short*)(ws + 19456);    // [128][128] bf16
    unsigned short* wt2f    = (unsigned short*)(ws + 52224);    // [128][128] bf16 (ends 84992)
    unsigned short* xb      = (unsigned short*)(ws + 84992);    // [100000][16] bf16, 3.2 MB

    prep_k<<<1024, 256, 0, stream>>>(x, W1, W2, wt1raw, wt2raw, xb, stats1);
    mlp_pass<0><<<GRID, 512, 0, stream>>>(xb, ei, wt1raw, nullptr, nullptr, nullptr,
                                          nullptr, nullptr, stats1, nullptr);
    fold_k<<<128, 128, 0, stream>>>(stats1, W1, 32, g1, be1, c1, wt1f);
    mlp_pass<1><<<GRID, 512, 0, stream>>>(xb, ei, wt1f, c1, wt2raw, nullptr,
                                          nullptr, nullptr, stats2, nullptr);
    fold_k<<<128, 128, 0, stream>>>(stats2, W2, 128, g2, be2, c2, wt2f);
    mlp_pass<2><<<GRID, 512, 0, stream>>>(xb, ei, wt1f, c1, wt2f, c2,
                                          W3, b3, nullptr, out);
}

// Round 17
// 154.021 us; speedup vs baseline: 2.2247x; 2.2247x over previous
//
#include <hip/hip_runtime.h>
#include <hip/hip_bf16.h>

// Problem constants (from setup_inputs)
#define N_NODES   100000
#define E_EDGES   1000000
#define H_DIM     128
#define NCHUNK    31250        // E / 32 edges per superchunk
#define GRID      256          // 256 blocks x 8 waves = 2048 wave-streams (r13-proven)
#define NWAVES    2048

typedef short bf16x8 __attribute__((ext_vector_type(8)));
typedef float f32x4  __attribute__((ext_vector_type(4)));

__device__ inline unsigned short f2bf(float f) {      // scalar RNE (cold paths only)
    unsigned u = __builtin_bit_cast(unsigned, f);
    u += 0x7fffu + ((u >> 16) & 1u);
    return (unsigned short)(u >> 16);
}

// Packed RNE f32x2 -> bf16x2 (r9-proven: cut VALUBusy 51->34)
__device__ inline unsigned pk2(float lo, float hi) {
    __hip_bfloat162 t = __float22bfloat162_rn(make_float2(lo, hi));
    unsigned lo16 = __bfloat16_as_ushort(t.x);
    unsigned hi16 = __bfloat16_as_ushort(t.y);
    return lo16 | (hi16 << 16);
}

__device__ inline f32x4 mfma16(bf16x8 a, bf16x8 b, f32x4 c) {
    return __builtin_amdgcn_mfma_f32_16x16x32_bf16(a, b, c, 0, 0, 0);
}

// Weights -> [j][k] bf16; x -> bf16 table (r11-proven: FETCH 58->17 MB); zero stats.
__global__ void prep_k(const float* __restrict__ x,
                       const float* __restrict__ W1, const float* __restrict__ W2,
                       unsigned short* __restrict__ wt1raw, unsigned short* __restrict__ wt2raw,
                       unsigned short* __restrict__ xb, float* __restrict__ stats) {
    int i = blockIdx.x * 256 + threadIdx.x;
    if (i < 512)   stats[i] = 0.f;                    // stats1[256] ++ stats2[256]
    if (i < 4096)  wt1raw[i] = f2bf(W1[(i & 31)  * H_DIM + (i >> 5)]);
    if (i < 16384) wt2raw[i] = f2bf(W2[(i & 127) * H_DIM + (i >> 7)]);
    const float4* x4 = (const float4*)x;
    uint2* xb2 = (uint2*)xb;
    for (int t = i; t < (N_NODES * 16) / 4; t += gridDim.x * 256) {
        float4 v = x4[t];
        uint2 o; o.x = pk2(v.x, v.y); o.y = pk2(v.z, v.w);
        xb2[t] = o;
    }
}

// stats -> BN fold. Parallel: block j (128 blocks), thread kp (128 threads).
// (off-hot-path change vs r13; mlp_pass codegen untouched)
__global__ void fold_k(const float* __restrict__ stats, const float* __restrict__ W, int K,
                       const float* __restrict__ gamma, const float* __restrict__ beta,
                       float* __restrict__ cvec, unsigned short* __restrict__ wtf) {
    int j  = blockIdx.x;
    int kp = threadIdx.x;
    const float invE = 1.0f / (float)E_EDGES;
    float s = stats[j], q = stats[128 + j];
    float mu  = s * invE;
    float var = fmaxf(q * invE - mu * mu, 0.f);        // clamp: corruption -> finite, not NaN
    float a   = gamma[j] * rsqrtf(var + 1e-5f);
    if (kp == 0) cvec[j] = beta[j] - mu * a;           // layer bias cancels inside BN
    if (kp < K)  wtf[j * K + kp] = f2bf(W[kp * H_DIM + j] * a);
}

// MODE 0: stats of d1 = ef@W1                         (raw wt1)
// MODE 1: h1' = relu(ef@W1f+c1); stats of d2 = h1'@W2 (raw wt2)
// MODE 2: full folded pipeline -> out = relu(h2')@W3 + b3
// 512-thread blocks (8 waves), r13-proven shape, r13-proven drain fence.
template<int MODE>
__global__ __launch_bounds__(512, 2) void mlp_pass(
    const unsigned short* __restrict__ xb, const int* __restrict__ ei,
    const unsigned short* __restrict__ wt1, const float* __restrict__ c1,
    const unsigned short* __restrict__ wt2, const float* __restrict__ c2,
    const float* __restrict__ w3, const float* __restrict__ b3,
    float* __restrict__ stats, float* __restrict__ out) {

    const int tid = threadIdx.x;
    const int w  = tid >> 6;        // wave 0..7
    const int l  = tid & 63;
    const int lm = l & 15;          // edge slot / row-within-tile
    const int lg = l >> 4;          // k-group (0..3)

    __shared__ __align__(16) unsigned char s_w2_[(MODE >= 1) ? 32768 : 16];
    __shared__ __align__(16) unsigned char s_h1_[(MODE >= 1) ? 65536 : 16];
    __shared__ float red_[(MODE <= 1) ? 2048 : 4];

    // Hoist layer-1 A fragments: A[j][k], j = jt*16+lm, k = lg*8..+7
    bf16x8 a1f[8];
#pragma unroll
    for (int jt = 0; jt < 8; jt++)
        a1f[jt] = *(const bf16x8*)(wt1 + (jt * 16 + lm) * 32 + lg * 8);

    if constexpr (MODE >= 1) {
        // Stage Wt2 [128][128] bf16 into LDS; 16B unit u of row j at slot u^(j&15)
        const uint4* g = (const uint4*)wt2;
        for (int i = tid; i < 2048; i += 512) {
            int j = i >> 4, u = i & 15;
            *(uint4*)(s_w2_ + j * 256 + ((u ^ (j & 15)) << 4)) = g[i];
        }
        __syncthreads();
    }

    float accS[8][4], accQ[8][4];
    if constexpr (MODE <= 1) {
#pragma unroll
        for (int jt = 0; jt < 8; jt++)
#pragma unroll
            for (int r = 0; r < 4; r++) { accS[jt][r] = 0.f; accQ[jt][r] = 0.f; }
    }

    unsigned char* myh = s_h1_ + w * 8192;
    const int eoff = (l >> 5) * E_EDGES;   // 0 -> src(row), 1 -> dst(col)
    const int f0   = (lg & 1) * 8;         // feature sub-offset within x row

    float b3v = 0.f;
    if constexpr (MODE == 2) b3v = b3[0];

    for (int sc = blockIdx.x * 8 + w; sc < NCHUNK; sc += NWAVES) {
        const int base = sc * 32;
        int iA = ei[eoff + base + lm];
        int iB = ei[eoff + base + 16 + lm];
        iA = min(max(iA, 0), N_NODES - 1);
        iB = min(max(iB, 0), N_NODES - 1);
        bf16x8 befA = *(const bf16x8*)(xb + (size_t)iA * 16 + f0);
        bf16x8 befB = *(const bf16x8*)(xb + (size_t)iB * 16 + f0);

        if constexpr (MODE == 0) {
#pragma unroll
            for (int jt = 0; jt < 8; jt++) {
                f32x4 z = {0.f, 0.f, 0.f, 0.f};
                f32x4 dA = mfma16(a1f[jt], befA, z);
                f32x4 dB = mfma16(a1f[jt], befB, z);
#pragma unroll
                for (int r = 0; r < 4; r++) {
                    accS[jt][r] += dA[r] + dB[r];
                    accQ[jt][r] += dA[r] * dA[r] + dB[r] * dB[r];
                }
            }
        } else {
            // ---- layer 1 (folded) + relu -> LDS (swizzled, pk2 packing) ----
#pragma unroll
            for (int jt = 0; jt < 8; jt++) {
                f32x4 z = {0.f, 0.f, 0.f, 0.f};
                f32x4 dA = mfma16(a1f[jt], befA, z);
                f32x4 dB = mfma16(a1f[jt], befB, z);
                float4 cv = *(const float4*)(c1 + jt * 16 + lg * 4);
                int uu  = jt * 2 + (lg >> 1);
                int off = lm * 256 + ((uu ^ (lm & 7)) << 4) + (lg & 1) * 8;
                {
                    uint2 pkv;
                    pkv.x = pk2(fmaxf(dA[0] + cv.x, 0.f), fmaxf(dA[1] + cv.y, 0.f));
                    pkv.y = pk2(fmaxf(dA[2] + cv.z, 0.f), fmaxf(dA[3] + cv.w, 0.f));
                    *(uint2*)(myh + off) = pkv;
                }
                {
                    uint2 pkv;
                    pkv.x = pk2(fmaxf(dB[0] + cv.x, 0.f), fmaxf(dB[1] + cv.y, 0.f));
                    pkv.y = pk2(fmaxf(dB[2] + cv.z, 0.f), fmaxf(dB[3] + cv.w, 0.f));
                    *(uint2*)(myh + 4096 + off) = pkv;
                }
            }
            // Load-bearing fence (r16 lesson): the memory clobber partitions the
            // ds_write cluster from the ds_read/MFMA cluster — without it the
            // scheduler inflates live ranges -> scratch storm (347 MB FETCH).
            asm volatile("s_waitcnt lgkmcnt(0)" ::: "memory");

            // ---- read back h1' B fragments ----
            bf16x8 hbA[4], hbB[4];
#pragma unroll
            for (int kt = 0; kt < 4; kt++) {
                int offr = lm * 256 + (((kt * 4 + lg) ^ (lm & 7)) << 4);
                hbA[kt] = *(const bf16x8*)(myh + offr);
                hbB[kt] = *(const bf16x8*)(myh + 4096 + offr);
            }

            // ---- layer 2 (K=128 as 4 x K=32, from LDS-staged W2) ----
            float sA = 0.f, sB = 0.f;
#pragma unroll
            for (int j2t = 0; j2t < 8; j2t++) {
                f32x4 dA2 = {0.f, 0.f, 0.f, 0.f}, dB2 = {0.f, 0.f, 0.f, 0.f};
                const int rb = (j2t * 16 + lm) * 256;
#pragma unroll
                for (int kt = 0; kt < 4; kt++) {
                    bf16x8 a2 = *(const bf16x8*)(s_w2_ + rb + (((kt * 4 + lg) ^ lm) << 4));
                    dA2 = mfma16(a2, hbA[kt], dA2);
                    dB2 = mfma16(a2, hbB[kt], dB2);
                }
                if constexpr (MODE == 1) {
#pragma unroll
                    for (int r = 0; r < 4; r++) {
                        accS[j2t][r] += dA2[r] + dB2[r];
                        accQ[j2t][r] += dA2[r] * dA2[r] + dB2[r] * dB2[r];
                    }
                } else {
                    float4 cv = *(const float4*)(c2 + j2t * 16 + lg * 4);
                    float4 wv = *(const float4*)(w3 + j2t * 16 + lg * 4);
                    sA = fmaf(fmaxf(dA2[0] + cv.x, 0.f), wv.x, sA);
                    sA = fmaf(fmaxf(dA2[1] + cv.y, 0.f), wv.y, sA);
                    sA = fmaf(fmaxf(dA2[2] + cv.z, 0.f), wv.z, sA);
                    sA = fmaf(fmaxf(dA2[3] + cv.w, 0.f), wv.w, sA);
                    sB = fmaf(fmaxf(dB2[0] + cv.x, 0.f), wv.x, sB);
                    sB = fmaf(fmaxf(dB2[1] + cv.y, 0.f), wv.y, sB);
                    sB = fmaf(fmaxf(dB2[2] + cv.z, 0.f), wv.z, sB);
                    sB = fmaf(fmaxf(dB2[3] + cv.w, 0.f), wv.w, sB);
                }
            }
            if constexpr (MODE == 2) {
                sA += __shfl_xor(sA, 16); sA += __shfl_xor(sA, 32);
                sB += __shfl_xor(sB, 16); sB += __shfl_xor(sB, 32);
                if (lg == 0) {
                    out[base + lm]      = sA + b3v;
                    out[base + 16 + lm] = sB + b3v;
                }
            }
        }
    }

    if constexpr (MODE <= 1) {
        __syncthreads();
#pragma unroll
        for (int jt = 0; jt < 8; jt++)
#pragma unroll
            for (int r = 0; r < 4; r++) {
                float v = accS[jt][r];
                v += __shfl_xor(v, 1); v += __shfl_xor(v, 2);
                v += __shfl_xor(v, 4); v += __shfl_xor(v, 8);
                float q = accQ[jt][r];
                q += __shfl_xor(q, 1); q += __shfl_xor(q, 2);
                q += __shfl_xor(q, 4); q += __shfl_xor(q, 8);
                if (lm == 0) {
                    int j = jt * 16 + lg * 4 + r;
                    red_[w * 256 + j]       = v;
                    red_[w * 256 + 128 + j] = q;
                }
            }
        __syncthreads();
        if (tid < 256) {
            float acc = 0.f;
#pragma unroll
            for (int t = 0; t < 8; t++) acc += red_[t * 256 + tid];
            atomicAdd(&stats[tid], acc);
        }
    }
}

extern "C" void kernel_launch(void* const* d_in, const int* in_sizes, int n_in,
                              void* d_out, int out_size, void* d_ws, size_t ws_size,
                              hipStream_t stream) {
    const float* x   = (const float*)d_in[0];
    const int*   ei  = (const int*)d_in[1];     // harness passes integer inputs as int32
    const float* W1  = (const float*)d_in[2];
    const float* g1  = (const float*)d_in[4];
    const float* be1 = (const float*)d_in[5];
    const float* W2  = (const float*)d_in[6];
    const float* g2  = (const float*)d_in[8];
    const float* be2 = (const float*)d_in[9];
    const float* W3  = (const float*)d_in[10];
    const float* b3  = (const float*)d_in[11];
    float* out = (float*)d_out;

    char* ws = (char*)d_ws;                                     // 84992 + 3.2 MB
    float* stats1           = (float*)ws;                       // [256]
    float* stats2           = (float*)(ws + 1024);              // [256]
    float* c1               = (float*)(ws + 2048);              // [128]
    float* c2               = (float*)(ws + 2560);              // [128]
    unsigned short* wt1raw  = (unsigned short*)(ws + 3072);     // [128][32]  bf16
    unsigned short* wt1f    = (unsigned short*)(ws + 11264);    // [128][32]  bf16
    unsigned short* wt2raw  = (unsigned short*)(ws + 19456);    // [128][128] bf16
    unsigned short* wt2f    = (unsigned short*)(ws + 52224);    // [128][128] bf16 (ends 84992)
    unsigned short* xb      = (unsigned short*)(ws + 84992);    // [100000][16] bf16, 3.2 MB

    prep_k<<<1024, 256, 0, stream>>>(x, W1, W2, wt1raw, wt2raw, xb, stats1);
    mlp_pass<0><<<GRID, 512, 0, stream>>>(xb, ei, wt1raw, nullptr, nullptr, nullptr,
                                          nullptr, nullptr, stats1, nullptr);
    fold_k<<<128, 128, 0, stream>>>(stats1, W1, 32, g1, be1, c1, wt1f);
    mlp_pass<1><<<GRID, 512, 0, stream>>>(xb, ei, wt1f, c1, wt2raw, nullptr,
                                          nullptr, nullptr, stats2, nullptr);
    fold_k<<<128, 128, 0, stream>>>(stats2, W2, 128, g2, be2, c2, wt2f);
    mlp_pass<2><<<GRID, 512, 0, stream>>>(xb, ei, wt1f, c1, wt2f, c2,
                                          W3, b3, nullptr, out);
}